// Round 2
// baseline (334.863 us; speedup 1.0000x reference)
//
#include <hip/hip_runtime.h>
#include <hip/hip_bf16.h>

// Problem constants (match reference)
#define BB 4
#define LL 256
#define N1 64
#define DD 8
#define KK 6
#define OO 64
#define AA 64
#define FF 192
#define DK 48   // D*K

// Persistent device scratch for the separable logit tables.
// logit[b,i,j,d,k] = T1[b,i,dk] + T2[j-i,dk] + T3[b,j,dk]  (concat split of F=192)
__device__ float g_T1[BB * LL * DK];  // dot(input_1[b,i,:], anchors[:, :,   0: 64])
__device__ float g_T3[BB * LL * DK];  // dot(input_2[b,j,:], anchors[:, :,  64:128])
__device__ float g_T2[LL * DK];       // dot(pos_emb[delta,:], anchors[:, :,128:192])

// -------- Kernel 1: precompute the three logit tables --------
// grid = 2*B*L + L rows, 64 threads each (1 wave). Trivial cost (~7M MACs).
__global__ __launch_bounds__(64) void precompute_logits(
    const float* __restrict__ in1, const float* __restrict__ in2,
    const float* __restrict__ pos, const float* __restrict__ anchors) {
  const int r = blockIdx.x;
  const int t = threadIdx.x;
  const float* src;
  float* dst;
  int off;
  if (r < BB * LL) {
    src = in1 + r * N1;        dst = g_T1 + r * DK;        off = 0;
  } else if (r < 2 * BB * LL) {
    const int q = r - BB * LL;
    src = in2 + q * N1;        dst = g_T3 + q * DK;        off = 64;
  } else {
    const int q = r - 2 * BB * LL;
    src = pos + q * N1;        dst = g_T2 + q * DK;        off = 128;
  }
  __shared__ float x[64];
  x[t] = src[t];
  __syncthreads();
  if (t < DK) {
    const float* av = anchors + t * FF + off;  // anchors[(d*6+k)][off + f]
    float s = 0.f;
#pragma unroll
    for (int f = 0; f < 64; ++f) s = fmaf(x[f], av[f], s);
    dst[t] = s;
  }
}

// -------- Kernel 2: main pair kernel --------
// Block (b,j): 256 threads, thread tid handles pair i=tid (if tid<j).
// logits come from the 3 tables; prob expansion via 6-stage doubling;
// 512x64 matvec with lut_weights read THREAD-UNIFORMLY (-> s_load) in
// uniform control flow; inactive lanes clamped then masked to zero.
__global__ __launch_bounds__(256) void lut_pairs_kernel(
    const float* __restrict__ lutw, float* __restrict__ out) {
  const int tid = threadIdx.x;
  const int bj = blockIdx.x;       // = b*L + j
  const int j = bj & (LL - 1);

  __shared__ float lds_l3[DK];
  __shared__ float lds_out[OO];
  if (tid < DK) lds_l3[tid] = g_T3[bj * DK + tid];
  if (tid < OO) lds_out[tid] = 0.f;
  __syncthreads();

  const bool active = (tid < j);
  const int i = active ? tid : 0;
  const int delta = active ? (j - tid) : 1;

  float acc[OO];
#pragma unroll
  for (int o = 0; o < OO; ++o) acc[o] = 0.f;

  const int b = bj >> 8;
  const float* l1base = g_T1 + (b * LL + i) * DK;
  const float* l2base = g_T2 + delta * DK;

#pragma unroll 1
  for (int d = 0; d < DD; ++d) {
    // 6 sigmoids for this detector
    float s1[KK], s0[KK];
#pragma unroll
    for (int k = 0; k < KK; ++k) {
      const float lg = l1base[d * KK + k] + l2base[d * KK + k] + lds_l3[d * KK + k];
      const float sg = __fdividef(1.f, 1.f + __expf(-lg));
      s1[k] = sg;
      s0[k] = 1.f - sg;
    }
    // expand to 64 address probabilities: pr[a] = prod_k (a>>k&1 ? s1[k] : s0[k])
    float pr[AA];
    pr[0] = 1.f;
#pragma unroll
    for (int k = 0; k < KK; ++k) {
      const int sz = 1 << k;
#pragma unroll
      for (int m = 0; m < sz; ++m) {
        pr[m + sz] = pr[m] * s1[k];
        pr[m] = pr[m] * s0[k];
      }
    }
    // matvec: acc[o] += sum_a pr[a] * W[d][a][o]
    // W address is thread-uniform (a,o compile-time; d uniform loop var) -> s_load.
    const float* wd = lutw + (d << 12);
#pragma unroll
    for (int a = 0; a < AA; ++a) {
      const float pa = pr[a];
#pragma unroll
      for (int o = 0; o < OO; ++o)
        acc[o] = fmaf(pa, wd[(a << 6) + o], acc[o]);
    }
  }

  // zero out contributions from clamped (inactive) lanes
  const float msk = active ? 1.f : 0.f;

  // reduce across the 256 threads (pairs) of the block
#pragma unroll
  for (int o = 0; o < OO; ++o) {
    float v = acc[o] * msk;
    v += __shfl_xor(v, 1);
    v += __shfl_xor(v, 2);
    v += __shfl_xor(v, 4);
    v += __shfl_xor(v, 8);
    v += __shfl_xor(v, 16);
    v += __shfl_xor(v, 32);
    if ((tid & 63) == 0) atomicAdd(&lds_out[o], v);
  }
  __syncthreads();
  if (tid < OO) out[bj * OO + tid] = lds_out[tid];
}

extern "C" void kernel_launch(void* const* d_in, const int* in_sizes, int n_in,
                              void* d_out, int out_size, void* d_ws, size_t ws_size,
                              hipStream_t stream) {
  const float* in1  = (const float*)d_in[0];   // input_1 [B,L,64]
  const float* in2  = (const float*)d_in[1];   // input_2 [B,L,64]
  const float* pos  = (const float*)d_in[2];   // pos_emb [L,64]
  const float* anc  = (const float*)d_in[3];   // anchors [8,6,192]
  const float* lutw = (const float*)d_in[4];   // lut_weights [8,64,64]
  float* out = (float*)d_out;                  // [B,L,64]

  precompute_logits<<<2 * BB * LL + LL, 64, 0, stream>>>(in1, in2, pos, anc);
  lut_pairs_kernel<<<BB * LL, 256, 0, stream>>>(lutw, out);
}

// Round 3
// 108.381 us; speedup vs baseline: 3.0897x; 3.0897x over previous
//
#include <hip/hip_runtime.h>
#include <hip/hip_bf16.h>

// Problem constants (match reference)
#define BB 4
#define LL 256
#define N1 64
#define DD 8
#define KK 6
#define OO 64
#define AA 64
#define FF 192
#define DK 48   // D*K

// Separable logit tables: logit[b,i,j,d,k] = T1[b,i,dk] + T2[j-i,dk] + T3[b,j,dk]
__device__ float g_T1[BB * LL * DK];  // dot(input_1[b,i,:], anchors[:, :,   0: 64])
__device__ float g_T3[BB * LL * DK];  // dot(input_2[b,j,:], anchors[:, :,  64:128])
__device__ float g_T2[LL * DK];       // dot(pos_emb[delta,:], anchors[:, :,128:192])

// -------- Kernel 1: precompute the three logit tables (unchanged, validated) ----
__global__ __launch_bounds__(64) void precompute_logits(
    const float* __restrict__ in1, const float* __restrict__ in2,
    const float* __restrict__ pos, const float* __restrict__ anchors) {
  const int r = blockIdx.x;
  const int t = threadIdx.x;
  const float* src;
  float* dst;
  int off;
  if (r < BB * LL) {
    src = in1 + r * N1;        dst = g_T1 + r * DK;        off = 0;
  } else if (r < 2 * BB * LL) {
    const int q = r - BB * LL;
    src = in2 + q * N1;        dst = g_T3 + q * DK;        off = 64;
  } else {
    const int q = r - 2 * BB * LL;
    src = pos + q * N1;        dst = g_T2 + q * DK;        off = 128;
  }
  __shared__ float x[64];
  x[t] = src[t];
  __syncthreads();
  if (t < DK) {
    const float* av = anchors + t * FF + off;
    float s = 0.f;
#pragma unroll
    for (int f = 0; f < 64; ++f) s = fmaf(x[f], av[f], s);
    dst[t] = s;
  }
}

// -------- Kernel 2: pair kernel with prob-sum-before-W (linearity) --------
// out[b,j,:] = (sum_{i<j} prob[i, d,a]) @ W.  Block=(b,j), 4 waves, lane=pair.
// Per (wave,d): doubling expansion in XOR-permuted order (cur[m] = pr[m^lane]),
// then 6-stage shfl_xor butterfly with static register indices -> lane holds
// q[a=lane] = sum over the wave's 64 pairs. No runtime-indexed arrays (rule #20).
__global__ __launch_bounds__(256, 3) void lut_pairs_kernel(
    const float* __restrict__ lutw, float* __restrict__ out) {
  const int tid  = threadIdx.x;
  const int lane = tid & 63;
  const int wv   = tid >> 6;          // wave 0..3
  const int bj   = blockIdx.x;        // b*L + j
  const int j    = bj & (LL - 1);
  const int b    = bj >> 8;

  __shared__ float q[4 * 512];        // per-wave q regions
  __shared__ float red[256];          // matvec quarter partials

#pragma unroll
  for (int t = 0; t < 8; ++t) q[tid + t * 256] = 0.f;
  __syncthreads();

  if (wv * 64 < j) {                  // wave-uniform activity test
    const int i     = wv * 64 + lane;
    const bool act  = i < j;
    const int ic    = act ? i : 0;
    const int delta = j - ic;         // in [1, 255]

    // 48 logits for this pair (float4 loads; rows are 192B = 12x float4)
    float l[DK];
    {
      const float4* p1 = (const float4*)(g_T1 + (b * LL + ic) * DK);
      const float4* p2 = (const float4*)(g_T2 + delta * DK);
      const float4* p3 = (const float4*)(g_T3 + (b * LL + j) * DK);  // wave-uniform
#pragma unroll
      for (int t = 0; t < 12; ++t) {
        const float4 a = p1[t], c = p2[t], e = p3[t];
        l[4 * t + 0] = a.x + c.x + e.x;
        l[4 * t + 1] = a.y + c.y + e.y;
        l[4 * t + 2] = a.z + c.z + e.z;
        l[4 * t + 3] = a.w + c.w + e.w;
      }
    }

    const float base = act ? 1.f : 0.f;   // masks inactive pairs out of the sum

#pragma unroll 1
    for (int d = 0; d < DD; ++d) {
      // factor pairs, pre-flipped per lane bit so cur[m] = pr[m ^ lane]
      float F0[KK], F1[KK];
#pragma unroll
      for (int k = 0; k < KK; ++k) {
        const float lg = l[d * KK + k];
        const float s1 = __fdividef(1.f, 1.f + __expf(-lg));
        const float s0 = 1.f - s1;
        const bool bk  = (lane >> k) & 1;
        F1[k] = bk ? s0 : s1;
        F0[k] = bk ? s1 : s0;
      }
      // doubling expansion: cur[m] = base * prod_k (bit_k(m) ? F1[k] : F0[k])
      float cur[AA];
      cur[0] = base;
#pragma unroll
      for (int k = 0; k < KK; ++k) {
        const int sz = 1 << k;
#pragma unroll
        for (int m = 0; m < sz; ++m) {
          cur[m + sz] = cur[m] * F1[k];
          cur[m]      = cur[m] * F0[k];
        }
      }
      // butterfly reduce-scatter over the wave: after 6 stages lane holds
      // cur[0] = sum over 64 lanes of pr[a = lane]
#pragma unroll
      for (int k = 0; k < KK; ++k) {
        const int st = 1 << k;
#pragma unroll
        for (int m = 0; m < AA; m += 2 * st)
          cur[m] += __shfl_xor(cur[m + st], st);
      }
      q[wv * 512 + d * 64 + lane] = cur[0];
    }
  }
  __syncthreads();

  // combine the 4 wave regions into region 0
#pragma unroll
  for (int t = 0; t < 2; ++t) {
    const int s = tid + t * 256;
    q[s] = q[s] + q[512 + s] + q[1024 + s] + q[1536 + s];
  }
  __syncthreads();

  // matvec: quarter = wave, o = lane.  W reads coalesced (lane = o), L2-resident.
  float acc = 0.f;
  const float* wq = lutw + (wv * 128) * OO + lane;
#pragma unroll 4
  for (int s = 0; s < 128; ++s)
    acc = fmaf(q[wv * 128 + s], wq[s * OO], acc);
  red[tid] = acc;
  __syncthreads();
  if (tid < OO)
    out[bj * OO + tid] = red[tid] + red[64 + tid] + red[128 + tid] + red[192 + tid];
}

extern "C" void kernel_launch(void* const* d_in, const int* in_sizes, int n_in,
                              void* d_out, int out_size, void* d_ws, size_t ws_size,
                              hipStream_t stream) {
  const float* in1  = (const float*)d_in[0];   // input_1 [B,L,64]
  const float* in2  = (const float*)d_in[1];   // input_2 [B,L,64]
  const float* pos  = (const float*)d_in[2];   // pos_emb [L,64]
  const float* anc  = (const float*)d_in[3];   // anchors [8,6,192]
  const float* lutw = (const float*)d_in[4];   // lut_weights [8,64,64]
  float* out = (float*)d_out;                  // [B,L,64]

  precompute_logits<<<2 * BB * LL + LL, 64, 0, stream>>>(in1, in2, pos, anc);
  lut_pairs_kernel<<<BB * LL, 256, 0, stream>>>(lutw, out);
}

// Round 4
// 96.416 us; speedup vs baseline: 3.4731x; 1.1241x over previous
//
#include <hip/hip_runtime.h>
#include <hip/hip_bf16.h>

// Problem constants (match reference)
#define BB 4
#define LL 256
#define N1 64
#define DD 8
#define KK 6
#define OO 64
#define AA 64
#define FF 192
#define DK 48   // D*K

#define R1 1024  // rows in T1 / T3
#define R2 256   // rows in T2
#define RPB 5    // rows per block in kernel 1
#define NB1 205  // ceil(1024/5)
#define NB2 52   // ceil(256/5)

// Separable logit tables: logit[b,i,j,d,k] = T1[b,i,dk] + T2[j-i,dk] + T3[b,j,dk]
__device__ float g_T1[R1 * DK];  // dot(input_1[b,i,:], anchors[:, :,   0: 64])
__device__ float g_T3[R1 * DK];  // dot(input_2[b,j,:], anchors[:, :,  64:128])
__device__ float g_T2[R2 * DK];  // dot(pos_emb[delta,:], anchors[:, :,128:192])

// -------- Kernel 1: precompute the three logit tables --------
// 462 blocks x 256 threads, 5 rows/block. Anchors slice staged in LDS with
// stride-65 padding (bank = (dk+f)%32, only free 2-way aliasing). Coalesced
// global loads; thread = (row_local, dk).
__global__ __launch_bounds__(256) void precompute_logits(
    const float* __restrict__ in1, const float* __restrict__ in2,
    const float* __restrict__ pos, const float* __restrict__ anchors) {
  const int bid = blockIdx.x;
  const int tid = threadIdx.x;
  const float* src;
  float* dst;
  int off, row0, nrows;
  if (bid < NB1) {
    src = in1; dst = g_T1; off = 0;   row0 = bid * RPB;             nrows = R1;
  } else if (bid < 2 * NB1) {
    src = in2; dst = g_T3; off = 64;  row0 = (bid - NB1) * RPB;     nrows = R1;
  } else {
    src = pos; dst = g_T2; off = 128; row0 = (bid - 2 * NB1) * RPB; nrows = R2;
  }

  __shared__ float as[DK * 65];
  __shared__ float xs[RPB * 64];
#pragma unroll
  for (int idx = tid; idx < DK * 64; idx += 256) {
    const int dk = idx >> 6, f = idx & 63;
    as[dk * 65 + f] = anchors[dk * FF + off + f];
  }
#pragma unroll
  for (int idx = tid; idx < RPB * 64; idx += 256) {
    const int rl = idx >> 6, f = idx & 63, r = row0 + rl;
    xs[idx] = (r < nrows) ? src[r * 64 + f] : 0.f;
  }
  __syncthreads();

  if (tid < RPB * DK) {
    const int rl = tid / DK, dk = tid - rl * DK, r = row0 + rl;
    float acc = 0.f;
#pragma unroll
    for (int f = 0; f < 64; ++f)
      acc = fmaf(xs[rl * 64 + f], as[dk * 65 + f], acc);
    if (r < nrows) dst[r * DK + dk] = acc;
  }
}

// -------- Kernel 2: pair kernel, prob-sum-before-W (linearity) --------
// out[b,j,:] = (sum_{i<j} prob[i,d,a]) @ W.  Block=(b,j), 4 waves, lane=pair.
// NO runtime-indexed register arrays (rule #20): logits are loaded per-d
// directly from the tables (float2 x3 from T1-row and T2-row, L1-resident
// after d=0; T3-row via LDS broadcast). F0/F1/cur all statically indexed.
// Per (wave,d): doubling expansion in XOR-permuted order (cur[m]=pr[m^lane]),
// then 6-stage shfl_xor butterfly -> lane holds q[a=lane] summed over pairs.
__global__ __launch_bounds__(256, 3) void lut_pairs_kernel(
    const float* __restrict__ lutw, float* __restrict__ out) {
  const int tid  = threadIdx.x;
  const int lane = tid & 63;
  const int wv   = tid >> 6;          // wave 0..3
  const int bj   = blockIdx.x;        // b*L + j
  const int j    = bj & (LL - 1);
  const int b    = bj >> 8;

  __shared__ float l3[DK];            // T3 row j (wave-uniform)
  __shared__ float q[4 * 512];        // per-wave q regions
  __shared__ float red[256];          // matvec quarter partials

  if (tid < DK) l3[tid] = g_T3[bj * DK + tid];
#pragma unroll
  for (int t = 0; t < 8; ++t) q[tid + t * 256] = 0.f;
  __syncthreads();

  if (wv * 64 < j) {                  // wave-uniform activity test
    const int i     = wv * 64 + lane;
    const bool act  = i < j;
    const int ic    = act ? i : 0;
    const int delta = j - ic;         // in [1, 255]

    const float* r1 = g_T1 + (b * LL + ic) * DK;
    const float* r2 = g_T2 + delta * DK;
    const float base = act ? 1.f : 0.f;  // masks inactive pairs out of the sum

#pragma unroll 1
    for (int d = 0; d < DD; ++d) {
      // 6 logits for this (pair, d): float2 loads (24B-aligned offsets)
      const float2 a0 = *(const float2*)(r1 + d * KK + 0);
      const float2 a1 = *(const float2*)(r1 + d * KK + 2);
      const float2 a2 = *(const float2*)(r1 + d * KK + 4);
      const float2 c0 = *(const float2*)(r2 + d * KK + 0);
      const float2 c1 = *(const float2*)(r2 + d * KK + 2);
      const float2 c2 = *(const float2*)(r2 + d * KK + 4);
      float lg[KK];
      lg[0] = a0.x + c0.x + l3[d * KK + 0];
      lg[1] = a0.y + c0.y + l3[d * KK + 1];
      lg[2] = a1.x + c1.x + l3[d * KK + 2];
      lg[3] = a1.y + c1.y + l3[d * KK + 3];
      lg[4] = a2.x + c2.x + l3[d * KK + 4];
      lg[5] = a2.y + c2.y + l3[d * KK + 5];

      // factor pairs, pre-flipped per lane bit so cur[m] = pr[m ^ lane]
      float F0[KK], F1[KK];
#pragma unroll
      for (int k = 0; k < KK; ++k) {
        const float s1 = __fdividef(1.f, 1.f + __expf(-lg[k]));
        const float s0 = 1.f - s1;
        const bool bk  = (lane >> k) & 1;
        F1[k] = bk ? s0 : s1;
        F0[k] = bk ? s1 : s0;
      }
      // doubling expansion: cur[m] = base * prod_k (bit_k(m) ? F1[k] : F0[k])
      float cur[AA];
      cur[0] = base;
#pragma unroll
      for (int k = 0; k < KK; ++k) {
        const int sz = 1 << k;
#pragma unroll
        for (int m = 0; m < sz; ++m) {
          cur[m + sz] = cur[m] * F1[k];
          cur[m]      = cur[m] * F0[k];
        }
      }
      // butterfly reduce-scatter over the wave: lane ends with
      // cur[0] = sum over 64 lanes of pr[a = lane]
#pragma unroll
      for (int k = 0; k < KK; ++k) {
        const int st = 1 << k;
#pragma unroll
        for (int m = 0; m < AA; m += 2 * st)
          cur[m] += __shfl_xor(cur[m + st], st);
      }
      q[wv * 512 + d * 64 + lane] = cur[0];
    }
  }
  __syncthreads();

  // combine the 4 wave regions into region 0
#pragma unroll
  for (int t = 0; t < 2; ++t) {
    const int s = tid + t * 256;
    q[s] = q[s] + q[512 + s] + q[1024 + s] + q[1536 + s];
  }
  __syncthreads();

  // matvec: quarter = wave, o = lane.  W reads coalesced (lane = o), L2-resident.
  float acc = 0.f;
  const float* wq = lutw + (wv * 128) * OO + lane;
#pragma unroll 4
  for (int s = 0; s < 128; ++s)
    acc = fmaf(q[wv * 128 + s], wq[s * OO], acc);
  red[tid] = acc;
  __syncthreads();
  if (tid < OO)
    out[bj * OO + tid] = red[tid] + red[64 + tid] + red[128 + tid] + red[192 + tid];
}

extern "C" void kernel_launch(void* const* d_in, const int* in_sizes, int n_in,
                              void* d_out, int out_size, void* d_ws, size_t ws_size,
                              hipStream_t stream) {
  const float* in1  = (const float*)d_in[0];   // input_1 [B,L,64]
  const float* in2  = (const float*)d_in[1];   // input_2 [B,L,64]
  const float* pos  = (const float*)d_in[2];   // pos_emb [L,64]
  const float* anc  = (const float*)d_in[3];   // anchors [8,6,192]
  const float* lutw = (const float*)d_in[4];   // lut_weights [8,64,64]
  float* out = (float*)d_out;                  // [B,L,64]

  precompute_logits<<<2 * NB1 + NB2, 256, 0, stream>>>(in1, in2, pos, anc);
  lut_pairs_kernel<<<BB * LL, 256, 0, stream>>>(lutw, out);
}

// Round 5
// 95.954 us; speedup vs baseline: 3.4898x; 1.0048x over previous
//
#include <hip/hip_runtime.h>
#include <hip/hip_bf16.h>

// Problem constants (match reference)
#define BB 4
#define LL 256
#define N1 64
#define DD 8
#define KK 6
#define OO 64
#define AA 64
#define FF 192
#define DK 48   // D*K

#define R1 1024  // rows in T1 / T3
#define R2 256   // rows in T2
#define RPB 5    // rows per block in kernel 1
#define NB1 205  // ceil(1024/5)
#define NB2 52   // ceil(256/5)

// Separable logit tables: logit[b,i,j,d,k] = T1[b,i,dk] + T2[j-i,dk] + T3[b,j,dk]
__device__ float g_T1[R1 * DK];  // dot(input_1[b,i,:], anchors[:, :,   0: 64])
__device__ float g_T3[R1 * DK];  // dot(input_2[b,j,:], anchors[:, :,  64:128])
__device__ float g_T2[R2 * DK];  // dot(pos_emb[delta,:], anchors[:, :,128:192])

// -------- Kernel 1: precompute the three logit tables (validated r4) --------
__global__ __launch_bounds__(256) void precompute_logits(
    const float* __restrict__ in1, const float* __restrict__ in2,
    const float* __restrict__ pos, const float* __restrict__ anchors) {
  const int bid = blockIdx.x;
  const int tid = threadIdx.x;
  const float* src;
  float* dst;
  int off, row0, nrows;
  if (bid < NB1) {
    src = in1; dst = g_T1; off = 0;   row0 = bid * RPB;             nrows = R1;
  } else if (bid < 2 * NB1) {
    src = in2; dst = g_T3; off = 64;  row0 = (bid - NB1) * RPB;     nrows = R1;
  } else {
    src = pos; dst = g_T2; off = 128; row0 = (bid - 2 * NB1) * RPB; nrows = R2;
  }

  __shared__ float as[DK * 65];
  __shared__ float xs[RPB * 64];
#pragma unroll
  for (int idx = tid; idx < DK * 64; idx += 256) {
    const int dk = idx >> 6, f = idx & 63;
    as[dk * 65 + f] = anchors[dk * FF + off + f];
  }
#pragma unroll
  for (int idx = tid; idx < RPB * 64; idx += 256) {
    const int rl = idx >> 6, f = idx & 63, r = row0 + rl;
    xs[idx] = (r < nrows) ? src[r * 64 + f] : 0.f;
  }
  __syncthreads();

  if (tid < RPB * DK) {
    const int rl = tid / DK, dk = tid - rl * DK, r = row0 + rl;
    float acc = 0.f;
#pragma unroll
    for (int f = 0; f < 64; ++f)
      acc = fmaf(xs[rl * 64 + f], as[dk * 65 + f], acc);
    if (r < nrows) dst[r * DK + dk] = acc;
  }
}

// -------- Kernel 2: pair kernel, prob-sum-before-W (linearity) --------
// Packed-f32 variant: doubling expansion runs on float2 (v_pk_mul_f32),
// pairing addresses (2p, 2p+1); stage k=0 folds into the packed init.
// Butterfly reduce-scatter unchanged in DS-op count (63, log-optimal),
// operating on statically-indexed packed components.
__global__ __launch_bounds__(256, 4) void lut_pairs_kernel(
    const float* __restrict__ lutw, float* __restrict__ out) {
  const int tid  = threadIdx.x;
  const int lane = tid & 63;
  const int wv   = tid >> 6;          // wave 0..3
  const int bj   = blockIdx.x;        // b*L + j
  const int j    = bj & (LL - 1);
  const int b    = bj >> 8;

  __shared__ float l3[DK];            // T3 row j (wave-uniform)
  __shared__ float q[4 * 512];        // per-wave q regions
  __shared__ float red[256];          // matvec quarter partials

  if (tid < DK) l3[tid] = g_T3[bj * DK + tid];
#pragma unroll
  for (int t = 0; t < 8; ++t) q[tid + t * 256] = 0.f;
  __syncthreads();

  if (wv * 64 < j) {                  // wave-uniform activity test
    const int i     = wv * 64 + lane;
    const bool act  = i < j;
    const int ic    = act ? i : 0;
    const int delta = j - ic;         // in [1, 255]

    const float* r1 = g_T1 + (b * LL + ic) * DK;
    const float* r2 = g_T2 + delta * DK;
    const float base = act ? 1.f : 0.f;  // masks inactive pairs out of the sum

#pragma unroll 1
    for (int d = 0; d < DD; ++d) {
      // 6 logits for this (pair, d): float2 loads (8B-aligned, 24B row offsets)
      const float2 a0 = *(const float2*)(r1 + d * KK + 0);
      const float2 a1 = *(const float2*)(r1 + d * KK + 2);
      const float2 a2 = *(const float2*)(r1 + d * KK + 4);
      const float2 c0 = *(const float2*)(r2 + d * KK + 0);
      const float2 c1 = *(const float2*)(r2 + d * KK + 2);
      const float2 c2 = *(const float2*)(r2 + d * KK + 4);
      float lg[KK];
      lg[0] = a0.x + c0.x + l3[d * KK + 0];
      lg[1] = a0.y + c0.y + l3[d * KK + 1];
      lg[2] = a1.x + c1.x + l3[d * KK + 2];
      lg[3] = a1.y + c1.y + l3[d * KK + 3];
      lg[4] = a2.x + c2.x + l3[d * KK + 4];
      lg[5] = a2.y + c2.y + l3[d * KK + 5];

      // factor pairs, pre-flipped per lane bit so cur[m] = pr[m ^ lane]
      float F0[KK], F1[KK];
#pragma unroll
      for (int k = 0; k < KK; ++k) {
        const float s1 = __fdividef(1.f, 1.f + __expf(-lg[k]));
        const float s0 = 1.f - s1;
        const bool bk  = (lane >> k) & 1;
        F1[k] = bk ? s0 : s1;
        F0[k] = bk ? s1 : s0;
      }

      // packed doubling expansion: cur2[p] = (cur[2p], cur[2p+1])
      // stage 0 folded into init; stages 1..5 are componentwise scalar muls
      // (v_pk_mul_f32-friendly), all indices static.
      float2 cur2[AA / 2];
      cur2[0].x = base * F0[0];
      cur2[0].y = base * F1[0];
#pragma unroll
      for (int k = 1; k < KK; ++k) {
        const int szp = 1 << (k - 1);
#pragma unroll
        for (int p = 0; p < szp; ++p) {
          cur2[p + szp].x = cur2[p].x * F1[k];
          cur2[p + szp].y = cur2[p].y * F1[k];
          cur2[p].x       = cur2[p].x * F0[k];
          cur2[p].y       = cur2[p].y * F0[k];
        }
      }

      // butterfly reduce-scatter across the wave (63 DS ops, log-optimal):
      // stage st=1 pairs packed components; stages 2..32 walk .x slots.
#pragma unroll
      for (int p = 0; p < 32; ++p)
        cur2[p].x += __shfl_xor(cur2[p].y, 1);
#pragma unroll
      for (int t = 0; t < 16; ++t)
        cur2[2 * t].x += __shfl_xor(cur2[2 * t + 1].x, 2);
#pragma unroll
      for (int t = 0; t < 8; ++t)
        cur2[4 * t].x += __shfl_xor(cur2[4 * t + 2].x, 4);
#pragma unroll
      for (int t = 0; t < 4; ++t)
        cur2[8 * t].x += __shfl_xor(cur2[8 * t + 4].x, 8);
#pragma unroll
      for (int t = 0; t < 2; ++t)
        cur2[16 * t].x += __shfl_xor(cur2[16 * t + 8].x, 16);
      cur2[0].x += __shfl_xor(cur2[16].x, 32);

      q[wv * 512 + d * 64 + lane] = cur2[0].x;
    }
  }
  __syncthreads();

  // combine the 4 wave regions into region 0
#pragma unroll
  for (int t = 0; t < 2; ++t) {
    const int s = tid + t * 256;
    q[s] = q[s] + q[512 + s] + q[1024 + s] + q[1536 + s];
  }
  __syncthreads();

  // matvec: quarter = wave, o = lane.  W reads coalesced (lane = o), L2-resident.
  float acc = 0.f;
  const float* wq = lutw + (wv * 128) * OO + lane;
#pragma unroll 4
  for (int s = 0; s < 128; ++s)
    acc = fmaf(q[wv * 128 + s], wq[s * OO], acc);
  red[tid] = acc;
  __syncthreads();
  if (tid < OO)
    out[bj * OO + tid] = red[tid] + red[64 + tid] + red[128 + tid] + red[192 + tid];
}

extern "C" void kernel_launch(void* const* d_in, const int* in_sizes, int n_in,
                              void* d_out, int out_size, void* d_ws, size_t ws_size,
                              hipStream_t stream) {
  const float* in1  = (const float*)d_in[0];   // input_1 [B,L,64]
  const float* in2  = (const float*)d_in[1];   // input_2 [B,L,64]
  const float* pos  = (const float*)d_in[2];   // pos_emb [L,64]
  const float* anc  = (const float*)d_in[3];   // anchors [8,6,192]
  const float* lutw = (const float*)d_in[4];   // lut_weights [8,64,64]
  float* out = (float*)d_out;                  // [B,L,64]

  precompute_logits<<<2 * NB1 + NB2, 256, 0, stream>>>(in1, in2, pos, anc);
  lut_pairs_kernel<<<BB * LL, 256, 0, stream>>>(lutw, out);
}

// Round 6
// 91.262 us; speedup vs baseline: 3.6693x; 1.0514x over previous
//
#include <hip/hip_runtime.h>
#include <hip/hip_bf16.h>

// Problem constants (match reference)
#define BB 4
#define LL 256
#define N1 64
#define DD 8
#define KK 6
#define OO 64
#define AA 64
#define FF 192
#define DK 48   // D*K

#define R1 1024  // rows in T1 / T3
#define R2 256   // rows in T2
#define RPB 5    // rows per block in kernel 1
#define NB1 205  // ceil(1024/5)
#define NB2 52   // ceil(256/5)

// Separable logit tables: logit[b,i,j,d,k] = T1[b,i,dk] + T2[j-i,dk] + T3[b,j,dk]
__device__ float g_T1[R1 * DK];  // dot(input_1[b,i,:], anchors[:, :,   0: 64])
__device__ float g_T3[R1 * DK];  // dot(input_2[b,j,:], anchors[:, :,  64:128])
__device__ float g_T2[R2 * DK];  // dot(pos_emb[delta,:], anchors[:, :,128:192])

// Cross-lane helpers (compile-time patterns; all lanes active at call sites).
template <int CTRL>
__device__ __forceinline__ float dpp_mov(float v) {
  return __int_as_float(__builtin_amdgcn_update_dpp(
      0, __float_as_int(v), CTRL, 0xF, 0xF, true));
}
template <int PAT>
__device__ __forceinline__ float swz(float v) {
  return __int_as_float(__builtin_amdgcn_ds_swizzle(__float_as_int(v), PAT));
}
#define DPP_XOR1 0xB1   // quad_perm [1,0,3,2]
#define DPP_XOR2 0x4E   // quad_perm [2,3,0,1]
#define DPP_XOR8 0x128  // row_ror:8  ((i+8)%16 == i^8)
#define SWZ_XOR4  0x101F
#define SWZ_XOR16 0x401F

// -------- Kernel 1: precompute the three logit tables (validated r4) --------
__global__ __launch_bounds__(256) void precompute_logits(
    const float* __restrict__ in1, const float* __restrict__ in2,
    const float* __restrict__ pos, const float* __restrict__ anchors) {
  const int bid = blockIdx.x;
  const int tid = threadIdx.x;
  const float* src;
  float* dst;
  int off, row0, nrows;
  if (bid < NB1) {
    src = in1; dst = g_T1; off = 0;   row0 = bid * RPB;             nrows = R1;
  } else if (bid < 2 * NB1) {
    src = in2; dst = g_T3; off = 64;  row0 = (bid - NB1) * RPB;     nrows = R1;
  } else {
    src = pos; dst = g_T2; off = 128; row0 = (bid - 2 * NB1) * RPB; nrows = R2;
  }

  __shared__ float as[DK * 65];
  __shared__ float xs[RPB * 64];
#pragma unroll
  for (int idx = tid; idx < DK * 64; idx += 256) {
    const int dk = idx >> 6, f = idx & 63;
    as[dk * 65 + f] = anchors[dk * FF + off + f];
  }
#pragma unroll
  for (int idx = tid; idx < RPB * 64; idx += 256) {
    const int rl = idx >> 6, f = idx & 63, r = row0 + rl;
    xs[idx] = (r < nrows) ? src[r * 64 + f] : 0.f;
  }
  __syncthreads();

  if (tid < RPB * DK) {
    const int rl = tid / DK, dk = tid - rl * DK, r = row0 + rl;
    float acc = 0.f;
#pragma unroll
    for (int f = 0; f < 64; ++f)
      acc = fmaf(xs[rl * 64 + f], as[dk * 65 + f], acc);
    if (r < nrows) dst[r * DK + dk] = acc;
  }
}

// -------- Kernel 2: pair kernel, prob-sum-before-W (linearity) --------
// Butterfly reduce-scatter now runs mostly on VALU DPP instead of the shared
// per-CU DS pipe. Stage order (1,2,8,4,16,32) is valid: every stage-s add
// combines values at the same address m^lane, independent of order; kept-slot
// bookkeeping tracked in comments. DS ops per (wave,d): 63 -> 7.
__global__ __launch_bounds__(256, 4) void lut_pairs_kernel(
    const float* __restrict__ lutw, float* __restrict__ out) {
  const int tid  = threadIdx.x;
  const int lane = tid & 63;
  const int wv   = tid >> 6;          // wave 0..3
  const int bj   = blockIdx.x;        // b*L + j
  const int j    = bj & (LL - 1);
  const int b    = bj >> 8;

  __shared__ float l3[DK];            // T3 row j (wave-uniform)
  __shared__ float q[4 * 512];        // per-wave q regions
  __shared__ float red[256];          // matvec quarter partials

  if (tid < DK) l3[tid] = g_T3[bj * DK + tid];
#pragma unroll
  for (int t = 0; t < 8; ++t) q[tid + t * 256] = 0.f;
  __syncthreads();

  if (wv * 64 < j) {                  // wave-uniform activity test
    const int i     = wv * 64 + lane;
    const bool act  = i < j;
    const int ic    = act ? i : 0;
    const int delta = j - ic;         // in [1, 255]

    const float* r1 = g_T1 + (b * LL + ic) * DK;
    const float* r2 = g_T2 + delta * DK;
    const float base = act ? 1.f : 0.f;  // masks inactive pairs out of the sum

#pragma unroll 1
    for (int d = 0; d < DD; ++d) {
      // 6 logits for this (pair, d): float2 loads (L1-resident after d=0)
      const float2 a0 = *(const float2*)(r1 + d * KK + 0);
      const float2 a1 = *(const float2*)(r1 + d * KK + 2);
      const float2 a2 = *(const float2*)(r1 + d * KK + 4);
      const float2 c0 = *(const float2*)(r2 + d * KK + 0);
      const float2 c1 = *(const float2*)(r2 + d * KK + 2);
      const float2 c2 = *(const float2*)(r2 + d * KK + 4);
      float lg[KK];
      lg[0] = a0.x + c0.x + l3[d * KK + 0];
      lg[1] = a0.y + c0.y + l3[d * KK + 1];
      lg[2] = a1.x + c1.x + l3[d * KK + 2];
      lg[3] = a1.y + c1.y + l3[d * KK + 3];
      lg[4] = a2.x + c2.x + l3[d * KK + 4];
      lg[5] = a2.y + c2.y + l3[d * KK + 5];

      // factor pairs, pre-flipped per lane bit so cur[m] = pr[m ^ lane]
      float F0[KK], F1[KK];
#pragma unroll
      for (int k = 0; k < KK; ++k) {
        const float s1 = __fdividef(1.f, 1.f + __expf(-lg[k]));
        const float s0 = 1.f - s1;
        const bool bk  = (lane >> k) & 1;
        F1[k] = bk ? s0 : s1;
        F0[k] = bk ? s1 : s0;
      }

      // packed doubling expansion: cur2[p] = (cur[2p], cur[2p+1]); stage 0
      // folded into the init; all indices static.
      float2 cur2[AA / 2];
      cur2[0].x = base * F0[0];
      cur2[0].y = base * F1[0];
#pragma unroll
      for (int k = 1; k < KK; ++k) {
        const int szp = 1 << (k - 1);
#pragma unroll
        for (int p = 0; p < szp; ++p) {
          cur2[p + szp].x = cur2[p].x * F1[k];
          cur2[p + szp].y = cur2[p].y * F1[k];
          cur2[p].x       = cur2[p].x * F0[k];
          cur2[p].y       = cur2[p].y * F0[k];
        }
      }

      // butterfly reduce-scatter, stage order (1,2,8,4,16,32):
      // s=1: 32 DPP adds; kept slots m even (= .x of each cur2[p])
#pragma unroll
      for (int p = 0; p < 32; ++p)
        cur2[p].x += dpp_mov<DPP_XOR1>(cur2[p].y);
      // s=2: 16 DPP adds; kept m % 4 == 0 (p even)
#pragma unroll
      for (int t = 0; t < 16; ++t)
        cur2[2 * t].x += dpp_mov<DPP_XOR2>(cur2[2 * t + 1].x);
      // s=8: 8 DPP adds; kept m in {0,4} mod 16 -> p in {0,2} mod 8, partner p+4
#pragma unroll
      for (int w = 0; w < 4; ++w) {
        cur2[8 * w + 0].x += dpp_mov<DPP_XOR8>(cur2[8 * w + 4].x);
        cur2[8 * w + 2].x += dpp_mov<DPP_XOR8>(cur2[8 * w + 6].x);
      }
      // s=4: 4 ds_swizzle; kept m in {0} mod 16 -> p in {0,8,16,24}, partner p+2
#pragma unroll
      for (int w = 0; w < 4; ++w)
        cur2[8 * w].x += swz<SWZ_XOR4>(cur2[8 * w + 2].x);
      // s=16: 2 ds_swizzle; kept m in {0,32} -> p in {0,16}, partner p+8
      cur2[0].x  += swz<SWZ_XOR16>(cur2[8].x);
      cur2[16].x += swz<SWZ_XOR16>(cur2[24].x);
      // s=32: crosses 32-lane halves -> bpermute-based shfl
      cur2[0].x += __shfl_xor(cur2[16].x, 32);

      q[wv * 512 + d * 64 + lane] = cur2[0].x;
    }
  }
  __syncthreads();

  // combine the 4 wave regions into region 0
#pragma unroll
  for (int t = 0; t < 2; ++t) {
    const int s = tid + t * 256;
    q[s] = q[s] + q[512 + s] + q[1024 + s] + q[1536 + s];
  }
  __syncthreads();

  // matvec: quarter = wave, o = lane.  W reads coalesced (lane = o), L2-resident.
  float acc = 0.f;
  const float* wq = lutw + (wv * 128) * OO + lane;
#pragma unroll 4
  for (int s = 0; s < 128; ++s)
    acc = fmaf(q[wv * 128 + s], wq[s * OO], acc);
  red[tid] = acc;
  __syncthreads();
  if (tid < OO)
    out[bj * OO + tid] = red[tid] + red[64 + tid] + red[128 + tid] + red[192 + tid];
}

extern "C" void kernel_launch(void* const* d_in, const int* in_sizes, int n_in,
                              void* d_out, int out_size, void* d_ws, size_t ws_size,
                              hipStream_t stream) {
  const float* in1  = (const float*)d_in[0];   // input_1 [B,L,64]
  const float* in2  = (const float*)d_in[1];   // input_2 [B,L,64]
  const float* pos  = (const float*)d_in[2];   // pos_emb [L,64]
  const float* anc  = (const float*)d_in[3];   // anchors [8,6,192]
  const float* lutw = (const float*)d_in[4];   // lut_weights [8,64,64]
  float* out = (float*)d_out;                  // [B,L,64]

  precompute_logits<<<2 * NB1 + NB2, 256, 0, stream>>>(in1, in2, pos, anc);
  lut_pairs_kernel<<<BB * LL, 256, 0, stream>>>(lutw, out);
}